// Round 20
// baseline (158.980 us; speedup 1.0000x reference)
//
#include <hip/hip_runtime.h>
#include <hip/hip_bf16.h>

#define S_LEN 2048
#define EMB 768
#define NH 12
#define HD 64
#define L2E 1.44269504088896340736f

typedef __attribute__((ext_vector_type(8))) short short8;
typedef __attribute__((ext_vector_type(4))) float f32x4;

typedef __attribute__((address_space(3))) void lds_t;
typedef __attribute__((address_space(1))) const void gbl_t;

__device__ __forceinline__ void gload16(const void* g, void* l) {
  __builtin_amdgcn_global_load_lds((gbl_t*)g, (lds_t*)l, 16, 0, 0);
}

__device__ __forceinline__ short f2bf(float f) {
  union { float f; unsigned u; } v; v.f = f;
  unsigned r = v.u + 0x7FFFu + ((v.u >> 16) & 1u);
  return (short)(r >> 16);
}

__device__ __forceinline__ unsigned pkbf(float a, float b) {
  unsigned r;
  asm("v_cvt_pk_bf16_f32 %0, %1, %2" : "=v"(r) : "v"(a), "v"(b));
  return r;
}

__global__ void cvt_bf16(const float* __restrict__ src, short* __restrict__ dst, int n) {
  int i = (blockIdx.x * blockDim.x + threadIdx.x) * 4;
  if (i >= n) return;
  float4 v = *reinterpret_cast<const float4*>(src + i);
  short4 o;
  o.x = f2bf(v.x); o.y = f2bf(v.y); o.z = f2bf(v.z); o.w = f2bf(v.w);
  *reinterpret_cast<short4*>(dst + i) = o;
}

__global__ void cvt_w(const float* __restrict__ Wq, const float* __restrict__ Wk,
                      const float* __restrict__ Wv, const float* __restrict__ Wo,
                      short* __restrict__ Wb, short* __restrict__ Wob) {
  int sec = blockIdx.y;
  const float* src = sec == 0 ? Wq : sec == 1 ? Wk : sec == 2 ? Wv : Wo;
  short* dst = sec < 3 ? Wb + sec * 589824 : Wob;
  int i = (blockIdx.x * blockDim.x + threadIdx.x) * 4;
  float4 v = *reinterpret_cast<const float4*>(src + i);
  short4 o;
  o.x = f2bf(v.x); o.y = f2bf(v.y); o.z = f2bf(v.z); o.w = f2bf(v.w);
  *reinterpret_cast<short4*>(dst + i) = o;
}

// NT GEMM v2: 128(M)x64(N) tile, 4 waves x (32x64). A staged in LDS (dbuf,
// lane-linear dest + XOR-swizzled source); B (weights, L2-resident) fragments
// read DIRECT from global. Grid 1152 (MODE0) -> 4.5 blocks/CU, ~18 waves/CU
// hide DMA + L2 latency (occupancy was the binding constraint at 2.25/CU).
template<int MODE>
__global__ __launch_bounds__(256)
void gemm_nt(const short* __restrict__ A, const short* __restrict__ B,
             float* __restrict__ outk, float* __restrict__ outv,
             short* __restrict__ qb, short* __restrict__ kb, short* __restrict__ vtb,
             float* __restrict__ outp, const float* __restrict__ bias) {
  const int K = EMB;
  const int NT = K / 64;
  __shared__ __align__(16) short As[2][128][64];
  int tid = threadIdx.x;
  int lane = tid & 63, wid = tid >> 6;
  int r16 = lane & 15, g4 = lane >> 4;
  int m0 = blockIdx.y * 128, n0 = blockIdx.x * 64;
  int lrow = lane >> 3, lchunk = lane & 7;
  int lcolsw = ((lchunk ^ lrow) * 8);   // pre-swizzled source column
  f32x4 acc[2][4] = {};

#define STAGEG(BUF, K0) do {                                          \
    _Pragma("unroll")                                                 \
    for (int i = 0; i < 4; i++) {                                     \
      int r = wid * 32 + i * 8 + lrow;                                \
      gload16(A + (long)(m0 + r) * K + (K0) + lcolsw, &As[BUF][r][lchunk * 8]); \
    } } while (0)

  STAGEG(0, 0);
  int cur = 0;
  for (int t = 0; t < NT; t++) {
    __syncthreads();  // drains A-DMA (vmcnt incl. B loads already consumed)
    if (t + 1 < NT) STAGEG(cur ^ 1, (t + 1) * 64);
    int k0 = t * 64;
#pragma unroll
    for (int s = 0; s < 2; s++) {
      int csw = ((s * 4 + g4) ^ (r16 & 7)) * 8;  // swizzled LDS read
      short8 af[2], bf[4];
#pragma unroll
      for (int mt = 0; mt < 2; mt++)
        af[mt] = *reinterpret_cast<const short8*>(&As[cur][wid * 32 + mt * 16 + r16][csw]);
#pragma unroll
      for (int nt = 0; nt < 4; nt++)
        bf[nt] = *reinterpret_cast<const short8*>(B + (long)(n0 + nt * 16 + r16) * K + k0 + s * 32 + g4 * 8);
#pragma unroll
      for (int mt = 0; mt < 2; mt++)
#pragma unroll
        for (int nt = 0; nt < 4; nt++)
          acc[mt][nt] = __builtin_amdgcn_mfma_f32_16x16x32_bf16(af[mt], bf[nt], acc[mt][nt], 0, 0, 0);
    }
    cur ^= 1;
  }
#undef STAGEG

#pragma unroll
  for (int mt = 0; mt < 2; mt++) {
    int nbase = m0 + wid * 32 + mt * 16 + g4 * 4;
#pragma unroll
    for (int nt = 0; nt < 4; nt++) {
      int f = n0 + nt * 16 + r16;
#pragma unroll
      for (int r = 0; r < 4; r++) {
        float c = acc[mt][nt][r];
        int nn = nbase + r;
        if (MODE == 0) {
          int b = nn >> 11, s = nn & 2047;
          int sec = f / EMB; int fh = f - sec * EMB;
          int h = fh >> 6, d = fh & 63;
          int idx = (((b * NH) + h) * S_LEN + s) * HD + d;
          if (sec == 0) qb[idx] = f2bf(c);
          else if (sec == 1) { outk[idx] = c; kb[idx] = f2bf(c); }
          else {
            outv[idx] = c;
            int bh = b * NH + h;  // V tiled [bh][kt64][d:64][k:64]
            vtb[((long)(bh * 32 + (s >> 6)) * 64 + d) * 64 + (s & 63)] = f2bf(c);
          }
        } else {
          outp[(long)nn * EMB + f] = c + bias[f];
        }
      }
    }
  }
}

// Flash attention v15 (proven): 4-wave block, 64 q-rows, K+V shared LDS
// staging (lane-linear dest + pre-swizzled source), 4 B per q-k pair.
__global__ __launch_bounds__(256)
void flash_attn15(const short* __restrict__ qb, const short* __restrict__ kb,
                  const short* __restrict__ vtb, short* __restrict__ mb) {
  const int tid = threadIdx.x;
  const int w = tid >> 6, lane = tid & 63;
  const int r16 = lane & 15, g4 = lane >> 4;
  const int id = blockIdx.x;
  const int xcd = id & 7, u = id >> 3;        // u in [0,96)
  const int bh = xcd + 8 * (u % 3);
  const int qt = 31 - u / 3;                  // longest first
  const int q0 = qt * 64 + w * 16;            // this wave's 16 q-rows
  const int nkt = qt + 1;                     // 64-row KV tiles (uniform)

  const short* qh = qb + (long)bh * S_LEN * HD;
  const short* kh = kb + (long)bh * S_LEN * HD;
  const short* vh = vtb + (long)bh * S_LEN * HD;  // [32 kt][64 d][64 k]

  __shared__ __align__(16) short KVl[2][2][64][64];  // [buf][K|V][row][col] 32KB
  __shared__ __align__(16) short Pa[4][16][40];
  __shared__ __align__(16) short Pb[4][16][40];
  __shared__ __align__(16) float sca_lds[4][16];
  float* Olds = (float*)&KVl[0][0][0][0];            // [4][16][68] epilogue alias

  const int srow = tid >> 3, schunk = tid & 7;
  const short* ksrc = kh + srow * HD + ((schunk ^ (srow & 7)) * 8);
  const short* vsrc = vh + srow * 64 + ((schunk ^ (srow & 7)) * 8);
#define STAGE(BUF, KT) do {                                          \
    long _off = (long)(KT) * 4096;                                   \
    gload16(ksrc + _off,           &KVl[BUF][0][srow][schunk * 8]);      \
    gload16(ksrc + _off + 32 * HD, &KVl[BUF][0][srow + 32][schunk * 8]); \
    gload16(vsrc + _off,           &KVl[BUF][1][srow][schunk * 8]);      \
    gload16(vsrc + _off + 32 * 64, &KVl[BUF][1][srow + 32][schunk * 8]); \
  } while (0)

  short8 qf0 = *reinterpret_cast<const short8*>(qh + (q0 + r16) * HD + g4 * 8);
  short8 qf1 = *reinterpret_cast<const short8*>(qh + (q0 + r16) * HD + 32 + g4 * 8);

  float m0 = -1e30f, m20 = -1.44e30f;
  float l0 = 0.f;                             // per-lane partial row sum
  f32x4 oacc[4] = {};

  const int kc0 = (g4 ^ (r16 & 7)) * 8;       // swizzled chunk offset (shorts)

  STAGE(0, 0);

  for (int kt = 0; kt < nkt; kt++) {
    __syncthreads();  // drains stage (vmcnt) -> buf[kt&1] resident; readers synced
    if (kt + 1 < nkt) STAGE((kt + 1) & 1, kt + 1);

    const short* kbuf = &KVl[kt & 1][0][0][0];
    const short* vbuf = &KVl[kt & 1][1][0][0];

    short8 k00 = *reinterpret_cast<const short8*>(kbuf + (r16) * 64 + kc0);
    short8 k01 = *reinterpret_cast<const short8*>(kbuf + (r16) * 64 + (kc0 ^ 32));
    short8 k10 = *reinterpret_cast<const short8*>(kbuf + (16 + r16) * 64 + kc0);
    short8 k11 = *reinterpret_cast<const short8*>(kbuf + (16 + r16) * 64 + (kc0 ^ 32));
    short8 k20 = *reinterpret_cast<const short8*>(kbuf + (32 + r16) * 64 + kc0);
    short8 k21 = *reinterpret_cast<const short8*>(kbuf + (32 + r16) * 64 + (kc0 ^ 32));
    short8 k30 = *reinterpret_cast<const short8*>(kbuf + (48 + r16) * 64 + kc0);
    short8 k31 = *reinterpret_cast<const short8*>(kbuf + (48 + r16) * 64 + (kc0 ^ 32));

    f32x4 s0 = {0.f, 0.f, 0.f, 0.f}, s1 = {0.f, 0.f, 0.f, 0.f};
    f32x4 s2 = {0.f, 0.f, 0.f, 0.f}, s3 = {0.f, 0.f, 0.f, 0.f};
    s0 = __builtin_amdgcn_mfma_f32_16x16x32_bf16(k00, qf0, s0, 0, 0, 0);
    s0 = __builtin_amdgcn_mfma_f32_16x16x32_bf16(k01, qf1, s0, 0, 0, 0);
    s1 = __builtin_amdgcn_mfma_f32_16x16x32_bf16(k10, qf0, s1, 0, 0, 0);
    s1 = __builtin_amdgcn_mfma_f32_16x16x32_bf16(k11, qf1, s1, 0, 0, 0);
    s2 = __builtin_amdgcn_mfma_f32_16x16x32_bf16(k20, qf0, s2, 0, 0, 0);
    s2 = __builtin_amdgcn_mfma_f32_16x16x32_bf16(k21, qf1, s2, 0, 0, 0);
    s3 = __builtin_amdgcn_mfma_f32_16x16x32_bf16(k30, qf0, s3, 0, 0, 0);
    s3 = __builtin_amdgcn_mfma_f32_16x16x32_bf16(k31, qf1, s3, 0, 0, 0);

    if (kt == nkt - 1) {  // diagonal tile: mask k > q (global indices)
      int qg = q0 + r16;
#pragma unroll
      for (int r = 0; r < 4; r++) {
        int kbase = kt * 64 + g4 * 4 + r;
        if (kbase > qg)      s0[r] = -1e30f;
        if (kbase + 16 > qg) s1[r] = -1e30f;
        if (kbase + 32 > qg) s2[r] = -1e30f;
        if (kbase + 48 > qg) s3[r] = -1e30f;
      }
    }

    float rm_local = fmaxf(
        fmaxf(fmaxf(fmaxf(s0[0], s0[1]), fmaxf(s0[2], s0[3])),
              fmaxf(fmaxf(s1[0], s1[1]), fmaxf(s1[2], s1[3]))),
        fmaxf(fmaxf(fmaxf(s2[0], s2[1]), fmaxf(s2[2], s2[3])),
              fmaxf(fmaxf(s3[0], s3[1]), fmaxf(s3[2], s3[3]))));

    if (!__all(rm_local <= m0 + 8.f)) {
      float x = rm_local;
      x = fmaxf(x, __shfl_xor(x, 16));
      x = fmaxf(x, __shfl_xor(x, 32));
      float nm = fmaxf(m0, x);
      float sca = __builtin_exp2f((m0 - nm) * L2E);
      m0 = nm; m20 = nm * L2E; l0 *= sca;
      if (g4 == 0) sca_lds[w][r16] = sca;
      f32x4 sr = *reinterpret_cast<const f32x4*>(&sca_lds[w][g4 * 4]);
#pragma unroll
      for (int dt = 0; dt < 4; dt++)
#pragma unroll
        for (int r = 0; r < 4; r++) oacc[dt][r] *= sr[r];
    }

    float rs = 0.f;
#pragma unroll
    for (int r = 0; r < 4; r++) {
      s0[r] = __builtin_exp2f(fmaf(s0[r], L2E, -m20));
      s1[r] = __builtin_exp2f(fmaf(s1[r], L2E, -m20));
      s2[r] = __builtin_exp2f(fmaf(s2[r], L2E, -m20));
      s3[r] = __builtin_exp2f(fmaf(s3[r], L2E, -m20));
      rs += (s0[r] + s1[r]) + (s2[r] + s3[r]);
    }
    l0 += rs;

    {
      uint2 wv;
      wv.x = pkbf(s0[0], s0[1]); wv.y = pkbf(s0[2], s0[3]);
      *reinterpret_cast<uint2*>(&Pa[w][r16][g4 * 4]) = wv;
      wv.x = pkbf(s1[0], s1[1]); wv.y = pkbf(s1[2], s1[3]);
      *reinterpret_cast<uint2*>(&Pa[w][r16][16 + g4 * 4]) = wv;
      wv.x = pkbf(s2[0], s2[1]); wv.y = pkbf(s2[2], s2[3]);
      *reinterpret_cast<uint2*>(&Pb[w][r16][g4 * 4]) = wv;
      wv.x = pkbf(s3[0], s3[1]); wv.y = pkbf(s3[2], s3[3]);
      *reinterpret_cast<uint2*>(&Pb[w][r16][16 + g4 * 4]) = wv;
    }
    short8 pa0 = *reinterpret_cast<const short8*>(&Pa[w][r16][g4 * 8]);
    short8 pa1 = *reinterpret_cast<const short8*>(&Pb[w][r16][g4 * 8]);

    short8 v00 = *reinterpret_cast<const short8*>(vbuf + (r16) * 64 + kc0);
    short8 v01 = *reinterpret_cast<const short8*>(vbuf + (r16) * 64 + (kc0 ^ 32));
    short8 v10 = *reinterpret_cast<const short8*>(vbuf + (16 + r16) * 64 + kc0);
    short8 v11 = *reinterpret_cast<const short8*>(vbuf + (16 + r16) * 64 + (kc0 ^ 32));
    short8 v20 = *reinterpret_cast<const short8*>(vbuf + (32 + r16) * 64 + kc0);
    short8 v21 = *reinterpret_cast<const short8*>(vbuf + (32 + r16) * 64 + (kc0 ^ 32));
    short8 v30 = *reinterpret_cast<const short8*>(vbuf + (48 + r16) * 64 + kc0);
    short8 v31 = *reinterpret_cast<const short8*>(vbuf + (48 + r16) * 64 + (kc0 ^ 32));

    oacc[0] = __builtin_amdgcn_mfma_f32_16x16x32_bf16(pa0, v00, oacc[0], 0, 0, 0);
    oacc[0] = __builtin_amdgcn_mfma_f32_16x16x32_bf16(pa1, v01, oacc[0], 0, 0, 0);
    oacc[1] = __builtin_amdgcn_mfma_f32_16x16x32_bf16(pa0, v10, oacc[1], 0, 0, 0);
    oacc[1] = __builtin_amdgcn_mfma_f32_16x16x32_bf16(pa1, v11, oacc[1], 0, 0, 0);
    oacc[2] = __builtin_amdgcn_mfma_f32_16x16x32_bf16(pa0, v20, oacc[2], 0, 0, 0);
    oacc[2] = __builtin_amdgcn_mfma_f32_16x16x32_bf16(pa1, v21, oacc[2], 0, 0, 0);
    oacc[3] = __builtin_amdgcn_mfma_f32_16x16x32_bf16(pa0, v30, oacc[3], 0, 0, 0);
    oacc[3] = __builtin_amdgcn_mfma_f32_16x16x32_bf16(pa1, v31, oacc[3], 0, 0, 0);
  }
#undef STAGE

  __syncthreads();  // all waves done with KVl before Olds aliasing

  {
    float rs = l0;
    rs += __shfl_xor(rs, 16);
    rs += __shfl_xor(rs, 32);
    if (g4 == 0) sca_lds[w][r16] = rs;
  }
  f32x4 li = *reinterpret_cast<const f32x4*>(&sca_lds[w][g4 * 4]);
  f32x4 iv;
#pragma unroll
  for (int r = 0; r < 4; r++) iv[r] = 1.f / li[r];
  float* Ow = Olds + w * 16 * 68;
#pragma unroll
  for (int dt = 0; dt < 4; dt++)
#pragma unroll
    for (int r = 0; r < 4; r++)
      Ow[(g4 * 4 + r) * 68 + dt * 16 + r16] = oacc[dt][r] * iv[r];
  {
    int orow = lane >> 2, oc = (lane & 3) * 16;
    int bb = bh / NH, h = bh % NH;
    f32x4 a0 = *reinterpret_cast<const f32x4*>(&Ow[orow * 68 + oc]);
    f32x4 a1 = *reinterpret_cast<const f32x4*>(&Ow[orow * 68 + oc + 4]);
    f32x4 a2 = *reinterpret_cast<const f32x4*>(&Ow[orow * 68 + oc + 8]);
    f32x4 a3 = *reinterpret_cast<const f32x4*>(&Ow[orow * 68 + oc + 12]);
    short8 sa, sb;
#pragma unroll
    for (int j = 0; j < 4; j++) {
      sa[j] = f2bf(a0[j]); sa[4 + j] = f2bf(a1[j]);
      sb[j] = f2bf(a2[j]); sb[4 + j] = f2bf(a3[j]);
    }
    short* dst = &mb[((long)(bb * S_LEN + q0 + orow)) * EMB + h * HD + oc];
    *reinterpret_cast<short8*>(dst) = sa;
    *reinterpret_cast<short8*>(dst + 8) = sb;
  }
}

extern "C" void kernel_launch(void* const* d_in, const int* in_sizes, int n_in,
                              void* d_out, int out_size, void* d_ws, size_t ws_size,
                              hipStream_t stream) {
  const float* x  = (const float*)d_in[0];
  const float* Wq = (const float*)d_in[1];
  const float* Wk = (const float*)d_in[2];
  const float* Wv = (const float*)d_in[3];
  const float* Wo = (const float*)d_in[4];
  const float* bo = (const float*)d_in[5];

  float* out  = (float*)d_out;
  float* outk = out + 3145728;
  float* outv = out + 6291456;

  short* ws  = (short*)d_ws;
  short* xb  = ws;                 // [4096][768]
  short* Wb  = xb + 3145728;       // [2304][768]  (Wq;Wk;Wv)
  short* Wob = Wb + 1769472;       // [768][768]
  short* qb  = Wob + 589824;       // [24][2048][64]
  short* kb  = qb + 3145728;       // [24][2048][64]
  short* vtb = kb + 3145728;       // [24][32][64][64]  (V tiled per 64-row KV tile)
  short* mb  = vtb + 3145728;      // [4096][768]    merged attn, bf16

  cvt_bf16<<<3072, 256, 0, stream>>>(x, xb, 3145728);
  cvt_w<<<dim3(576, 4), 256, 0, stream>>>(Wq, Wk, Wv, Wo, Wb, Wob);

  gemm_nt<0><<<dim3(36, 32), 256, 0, stream>>>(xb, Wb, outk, outv, qb, kb, vtb, nullptr, nullptr);
  flash_attn15<<<768, 256, 0, stream>>>(qb, kb, vtb, mb);
  gemm_nt<1><<<dim3(12, 32), 256, 0, stream>>>(mb, Wob, nullptr, nullptr, nullptr, nullptr, nullptr, out, bo);
}

// Round 21
// 103.446 us; speedup vs baseline: 1.5368x; 1.5368x over previous
//
#include <hip/hip_runtime.h>
#include <hip/hip_bf16.h>

#define S_LEN 2048
#define EMB 768
#define NH 12
#define HD 64
#define L2E 1.44269504088896340736f

typedef __attribute__((ext_vector_type(8))) short short8;
typedef __attribute__((ext_vector_type(4))) float f32x4;

typedef __attribute__((address_space(3))) void lds_t;
typedef __attribute__((address_space(1))) const void gbl_t;

__device__ __forceinline__ void gload16(const void* g, void* l) {
  __builtin_amdgcn_global_load_lds((gbl_t*)g, (lds_t*)l, 16, 0, 0);
}

__device__ __forceinline__ short f2bf(float f) {
  union { float f; unsigned u; } v; v.f = f;
  unsigned r = v.u + 0x7FFFu + ((v.u >> 16) & 1u);
  return (short)(r >> 16);
}

__device__ __forceinline__ unsigned pkbf(float a, float b) {
  unsigned r;
  asm("v_cvt_pk_bf16_f32 %0, %1, %2" : "=v"(r) : "v"(a), "v"(b));
  return r;
}

// fused input + weight conversion (single launch)
__global__ void cvt_all(const float* __restrict__ x,
                        const float* __restrict__ Wq, const float* __restrict__ Wk,
                        const float* __restrict__ Wv, const float* __restrict__ Wo,
                        short* __restrict__ xb, short* __restrict__ Wb,
                        short* __restrict__ Wob) {
  int bid = blockIdx.x, tid = threadIdx.x;
  const float* src;
  short* dst;
  int off;
  if (bid < 3072) {
    src = x; dst = xb; off = bid * 1024 + tid * 4;
  } else {
    int wb = bid - 3072;
    int sec = wb / 576;
    off = (wb % 576) * 1024 + tid * 4;
    src = sec == 0 ? Wq : sec == 1 ? Wk : sec == 2 ? Wv : Wo;
    dst = sec < 3 ? Wb + sec * 589824 : Wob;
  }
  float4 v = *reinterpret_cast<const float4*>(src + off);
  short4 o;
  o.x = f2bf(v.x); o.y = f2bf(v.y); o.z = f2bf(v.z); o.w = f2bf(v.w);
  *reinterpret_cast<short4*>(dst + off) = o;
}

// NT GEMM (R18 structure): dbuf global_load_lds staging + XOR swizzle +
// counted-vmcnt pipeline. MODE 0 adds an LDS-coalesced epilogue: C tile staged
// f32 in LDS (aliases As/Bs), then contiguous short8/float4 row stores per
// head; vtb written as packed short4 direct from registers.
template<int MODE>
__global__ __launch_bounds__(256)
void gemm_nt(const short* __restrict__ A, const short* __restrict__ B,
             float* __restrict__ outk, float* __restrict__ outv,
             short* __restrict__ qb, short* __restrict__ kb, short* __restrict__ vtb,
             float* __restrict__ outp, const float* __restrict__ bias) {
  const int K = EMB;
  const int NT = K / 64;
  __shared__ __align__(16) char RAW[128 * 132 * 4];   // 67.6 KB
  short (*As)[128][64] = (short(*)[128][64])RAW;                 // [2][128][64]
  short (*Bs)[128][64] = (short(*)[128][64])(RAW + 32768);       // [2][128][64]
  float (*Cl)[132] = (float(*)[132])RAW;                         // [128][132]
  int tid = threadIdx.x;
  int lane = tid & 63, wid = tid >> 6;
  int wm = wid >> 1, wn = wid & 1;
  int r16 = lane & 15, g4 = lane >> 4;
  int m0 = blockIdx.y * 128, n0 = blockIdx.x * 128;
  int lrow = lane >> 3, lchunk = lane & 7;
  int lcolsw = ((lchunk ^ lrow) * 8);   // pre-swizzled source column
  f32x4 acc[4][4] = {};

#define STAGEG(BUF, K0) do {                                          \
    _Pragma("unroll")                                                 \
    for (int i = 0; i < 4; i++) {                                     \
      int r = wid * 32 + i * 8 + lrow;                                \
      gload16(A + (long)(m0 + r) * K + (K0) + lcolsw, &As[BUF][r][lchunk * 8]); \
      gload16(B + (long)(n0 + r) * K + (K0) + lcolsw, &Bs[BUF][r][lchunk * 8]); \
    } } while (0)

  STAGEG(0, 0);
  int cur = 0;
  for (int t = 0; t < NT; t++) {
    if (t + 1 < NT) {
      STAGEG(cur ^ 1, (t + 1) * 64);
      asm volatile("s_waitcnt vmcnt(8)" ::: "memory");  // cur landed; next in flight
    } else {
      asm volatile("s_waitcnt vmcnt(0)" ::: "memory");
    }
    __builtin_amdgcn_sched_barrier(0);
    __builtin_amdgcn_s_barrier();       // all waves' cur-tile loads landed
    __builtin_amdgcn_sched_barrier(0);
#pragma unroll
    for (int s = 0; s < 2; s++) {
      int csw = ((s * 4 + g4) ^ (r16 & 7)) * 8;  // swizzled read
      short8 af[4], bf[4];
#pragma unroll
      for (int tt = 0; tt < 4; tt++) {
        af[tt] = *reinterpret_cast<const short8*>(&As[cur][wm * 64 + tt * 16 + r16][csw]);
        bf[tt] = *reinterpret_cast<const short8*>(&Bs[cur][wn * 64 + tt * 16 + r16][csw]);
      }
#pragma unroll
      for (int mt = 0; mt < 4; mt++)
#pragma unroll
        for (int nt = 0; nt < 4; nt++)
          acc[mt][nt] = __builtin_amdgcn_mfma_f32_16x16x32_bf16(af[mt], bf[nt], acc[mt][nt], 0, 0, 0);
    }
    __builtin_amdgcn_sched_barrier(0);
    __builtin_amdgcn_s_barrier();       // all waves done reading cur
    cur ^= 1;
  }
#undef STAGEG

  if (MODE == 1) {
#pragma unroll
    for (int mt = 0; mt < 4; mt++) {
      int nbase = m0 + wm * 64 + mt * 16 + g4 * 4;
#pragma unroll
      for (int nt = 0; nt < 4; nt++) {
        int f = n0 + wn * 64 + nt * 16 + r16;
#pragma unroll
        for (int r = 0; r < 4; r++)
          outp[(long)(nbase + r) * EMB + f] = acc[mt][nt][r] + bias[f];
      }
    }
    return;
  }

  // ---- MODE 0 epilogue: vtb direct (packed), rest via LDS-coalesced path ----
  const int bx = blockIdx.x;
  const int sec = bx / 6;               // 0=q 1=k 2=v (block fully in one section)
  const int h0 = (bx % 6) * 2;
  const int b = m0 >> 11, s0l = m0 & 2047;

  if (sec == 2) {  // vtb[((bh*32+sg>>6)*64+d)*64+(sg&63)]: 4 consecutive r -> short4
#pragma unroll
    for (int mt = 0; mt < 4; mt++) {
      int sg = s0l + wm * 64 + mt * 16 + g4 * 4;
#pragma unroll
      for (int nt = 0; nt < 4; nt++) {
        int fl = wn * 64 + nt * 16 + r16;
        int h = h0 + (fl >> 6), d = fl & 63;
        int bh = b * NH + h;
        short4 o;
        o.x = f2bf(acc[mt][nt][0]); o.y = f2bf(acc[mt][nt][1]);
        o.z = f2bf(acc[mt][nt][2]); o.w = f2bf(acc[mt][nt][3]);
        *reinterpret_cast<short4*>(
            &vtb[((long)(bh * 32 + (sg >> 6)) * 64 + d) * 64 + (sg & 63)]) = o;
      }
    }
  }

  // stage C tile (f32) into LDS; safe: last loop barrier synced all waves
#pragma unroll
  for (int mt = 0; mt < 4; mt++) {
    int rl = wm * 64 + mt * 16 + g4 * 4;
#pragma unroll
    for (int nt = 0; nt < 4; nt++) {
      int fl = wn * 64 + nt * 16 + r16;
#pragma unroll
      for (int r = 0; r < 4; r++) Cl[rl + r][fl] = acc[mt][nt][r];
    }
  }
  __syncthreads();

  {
    int row = tid >> 1, cb = (tid & 1) * 32;  // 32 f32 per thread per head
#pragma unroll
    for (int hh = 0; hh < 2; hh++) {
      const float* src = &Cl[row][hh * 64 + cb];
      long base = ((long)(b * NH + h0 + hh) * S_LEN + s0l) * HD + (long)row * 64 + cb;
      if (sec == 0) {
        short* dq = qb + base;
#pragma unroll
        for (int c = 0; c < 4; c++) {
          f32x4 a = *reinterpret_cast<const f32x4*>(src + c * 8);
          f32x4 bb = *reinterpret_cast<const f32x4*>(src + c * 8 + 4);
          short8 o;
#pragma unroll
          for (int j = 0; j < 4; j++) { o[j] = f2bf(a[j]); o[4 + j] = f2bf(bb[j]); }
          *reinterpret_cast<short8*>(dq + c * 8) = o;
        }
      } else if (sec == 1) {
        float* dk = outk + base;
        short* dkb = kb + base;
#pragma unroll
        for (int c = 0; c < 4; c++) {
          f32x4 a = *reinterpret_cast<const f32x4*>(src + c * 8);
          f32x4 bb = *reinterpret_cast<const f32x4*>(src + c * 8 + 4);
          *reinterpret_cast<f32x4*>(dk + c * 8) = a;
          *reinterpret_cast<f32x4*>(dk + c * 8 + 4) = bb;
          short8 o;
#pragma unroll
          for (int j = 0; j < 4; j++) { o[j] = f2bf(a[j]); o[4 + j] = f2bf(bb[j]); }
          *reinterpret_cast<short8*>(dkb + c * 8) = o;
        }
      } else {
        float* dv = outv + base;
#pragma unroll
        for (int c = 0; c < 8; c++)
          *reinterpret_cast<f32x4*>(dv + c * 4) =
              *reinterpret_cast<const f32x4*>(src + c * 4);
      }
    }
  }
}

// Flash attention v15 (proven): 4-wave block, 64 q-rows, K+V shared LDS
// staging (lane-linear dest + pre-swizzled source), 4 B per q-k pair.
__global__ __launch_bounds__(256)
void flash_attn15(const short* __restrict__ qb, const short* __restrict__ kb,
                  const short* __restrict__ vtb, short* __restrict__ mb) {
  const int tid = threadIdx.x;
  const int w = tid >> 6, lane = tid & 63;
  const int r16 = lane & 15, g4 = lane >> 4;
  const int id = blockIdx.x;
  const int xcd = id & 7, u = id >> 3;        // u in [0,96)
  const int bh = xcd + 8 * (u % 3);
  const int qt = 31 - u / 3;                  // longest first
  const int q0 = qt * 64 + w * 16;            // this wave's 16 q-rows
  const int nkt = qt + 1;                     // 64-row KV tiles (uniform)

  const short* qh = qb + (long)bh * S_LEN * HD;
  const short* kh = kb + (long)bh * S_LEN * HD;
  const short* vh = vtb + (long)bh * S_LEN * HD;  // [32 kt][64 d][64 k]

  __shared__ __align__(16) short KVl[2][2][64][64];  // [buf][K|V][row][col] 32KB
  __shared__ __align__(16) short Pa[4][16][40];
  __shared__ __align__(16) short Pb[4][16][40];
  __shared__ __align__(16) float sca_lds[4][16];
  float* Olds = (float*)&KVl[0][0][0][0];            // [4][16][68] epilogue alias

  const int srow = tid >> 3, schunk = tid & 7;
  const short* ksrc = kh + srow * HD + ((schunk ^ (srow & 7)) * 8);
  const short* vsrc = vh + srow * 64 + ((schunk ^ (srow & 7)) * 8);
#define STAGE(BUF, KT) do {                                          \
    long _off = (long)(KT) * 4096;                                   \
    gload16(ksrc + _off,           &KVl[BUF][0][srow][schunk * 8]);      \
    gload16(ksrc + _off + 32 * HD, &KVl[BUF][0][srow + 32][schunk * 8]); \
    gload16(vsrc + _off,           &KVl[BUF][1][srow][schunk * 8]);      \
    gload16(vsrc + _off + 32 * 64, &KVl[BUF][1][srow + 32][schunk * 8]); \
  } while (0)

  short8 qf0 = *reinterpret_cast<const short8*>(qh + (q0 + r16) * HD + g4 * 8);
  short8 qf1 = *reinterpret_cast<const short8*>(qh + (q0 + r16) * HD + 32 + g4 * 8);

  float m0 = -1e30f, m20 = -1.44e30f;
  float l0 = 0.f;                             // per-lane partial row sum
  f32x4 oacc[4] = {};

  const int kc0 = (g4 ^ (r16 & 7)) * 8;       // swizzled chunk offset (shorts)

  STAGE(0, 0);

  for (int kt = 0; kt < nkt; kt++) {
    __syncthreads();  // drains stage (vmcnt) -> buf[kt&1] resident; readers synced
    if (kt + 1 < nkt) STAGE((kt + 1) & 1, kt + 1);

    const short* kbuf = &KVl[kt & 1][0][0][0];
    const short* vbuf = &KVl[kt & 1][1][0][0];

    short8 k00 = *reinterpret_cast<const short8*>(kbuf + (r16) * 64 + kc0);
    short8 k01 = *reinterpret_cast<const short8*>(kbuf + (r16) * 64 + (kc0 ^ 32));
    short8 k10 = *reinterpret_cast<const short8*>(kbuf + (16 + r16) * 64 + kc0);
    short8 k11 = *reinterpret_cast<const short8*>(kbuf + (16 + r16) * 64 + (kc0 ^ 32));
    short8 k20 = *reinterpret_cast<const short8*>(kbuf + (32 + r16) * 64 + kc0);
    short8 k21 = *reinterpret_cast<const short8*>(kbuf + (32 + r16) * 64 + (kc0 ^ 32));
    short8 k30 = *reinterpret_cast<const short8*>(kbuf + (48 + r16) * 64 + kc0);
    short8 k31 = *reinterpret_cast<const short8*>(kbuf + (48 + r16) * 64 + (kc0 ^ 32));

    f32x4 s0 = {0.f, 0.f, 0.f, 0.f}, s1 = {0.f, 0.f, 0.f, 0.f};
    f32x4 s2 = {0.f, 0.f, 0.f, 0.f}, s3 = {0.f, 0.f, 0.f, 0.f};
    s0 = __builtin_amdgcn_mfma_f32_16x16x32_bf16(k00, qf0, s0, 0, 0, 0);
    s0 = __builtin_amdgcn_mfma_f32_16x16x32_bf16(k01, qf1, s0, 0, 0, 0);
    s1 = __builtin_amdgcn_mfma_f32_16x16x32_bf16(k10, qf0, s1, 0, 0, 0);
    s1 = __builtin_amdgcn_mfma_f32_16x16x32_bf16(k11, qf1, s1, 0, 0, 0);
    s2 = __builtin_amdgcn_mfma_f32_16x16x32_bf16(k20, qf0, s2, 0, 0, 0);
    s2 = __builtin_amdgcn_mfma_f32_16x16x32_bf16(k21, qf1, s2, 0, 0, 0);
    s3 = __builtin_amdgcn_mfma_f32_16x16x32_bf16(k30, qf0, s3, 0, 0, 0);
    s3 = __builtin_amdgcn_mfma_f32_16x16x32_bf16(k31, qf1, s3, 0, 0, 0);

    if (kt == nkt - 1) {  // diagonal tile: mask k > q (global indices)
      int qg = q0 + r16;
#pragma unroll
      for (int r = 0; r < 4; r++) {
        int kbase = kt * 64 + g4 * 4 + r;
        if (kbase > qg)      s0[r] = -1e30f;
        if (kbase + 16 > qg) s1[r] = -1e30f;
        if (kbase + 32 > qg) s2[r] = -1e30f;
        if (kbase + 48 > qg) s3[r] = -1e30f;
      }
    }

    float rm_local = fmaxf(
        fmaxf(fmaxf(fmaxf(s0[0], s0[1]), fmaxf(s0[2], s0[3])),
              fmaxf(fmaxf(s1[0], s1[1]), fmaxf(s1[2], s1[3]))),
        fmaxf(fmaxf(fmaxf(s2[0], s2[1]), fmaxf(s2[2], s2[3])),
              fmaxf(fmaxf(s3[0], s3[1]), fmaxf(s3[2], s3[3]))));

    if (!__all(rm_local <= m0 + 8.f)) {
      float x = rm_local;
      x = fmaxf(x, __shfl_xor(x, 16));
      x = fmaxf(x, __shfl_xor(x, 32));
      float nm = fmaxf(m0, x);
      float sca = __builtin_exp2f((m0 - nm) * L2E);
      m0 = nm; m20 = nm * L2E; l0 *= sca;
      if (g4 == 0) sca_lds[w][r16] = sca;
      f32x4 sr = *reinterpret_cast<const f32x4*>(&sca_lds[w][g4 * 4]);
#pragma unroll
      for (int dt = 0; dt < 4; dt++)
#pragma unroll
        for (int r = 0; r < 4; r++) oacc[dt][r] *= sr[r];
    }

    float rs = 0.f;
#pragma unroll
    for (int r = 0; r < 4; r++) {
      s0[r] = __builtin_exp2f(fmaf(s0[r], L2E, -m20));
      s1[r] = __builtin_exp2f(fmaf(s1[r], L2E, -m20));
      s2[r] = __builtin_exp2f(fmaf(s2[r], L2E, -m20));
      s3[r] = __builtin_exp2f(fmaf(s3[r], L2E, -m20));
      rs += (s0[r] + s1[r]) + (s2[r] + s3[r]);
    }
    l0 += rs;

    {
      uint2 wv;
      wv.x = pkbf(s0[0], s0[1]); wv.y = pkbf(s0[2], s0[3]);
      *reinterpret_cast<uint2*>(&Pa[w][r16][g4 * 4]) = wv;
      wv.x = pkbf(s1[0], s1[1]); wv.y = pkbf(s1[2], s1[3]);
      *reinterpret_cast<uint2*>(&Pa[w][r16][16 + g4 * 4]) = wv;
      wv.x = pkbf(s2[0], s2[1]); wv.y = pkbf(s2[2], s2[3]);
      *reinterpret_cast<uint2*>(&Pb[w][r16][g4 * 4]) = wv;
      wv.x = pkbf(s3[0], s3[1]); wv.y = pkbf(s3[2], s3[3]);
      *reinterpret_cast<uint2*>(&Pb[w][r16][16 + g4 * 4]) = wv;
    }
    short8 pa0 = *reinterpret_cast<const short8*>(&Pa[w][r16][g4 * 8]);
    short8 pa1 = *reinterpret_cast<const short8*>(&Pb[w][r16][g4 * 8]);

    short8 v00 = *reinterpret_cast<const short8*>(vbuf + (r16) * 64 + kc0);
    short8 v01 = *reinterpret_cast<const short8*>(vbuf + (r16) * 64 + (kc0 ^ 32));
    short8 v10 = *reinterpret_cast<const short8*>(vbuf + (16 + r16) * 64 + kc0);
    short8 v11 = *reinterpret_cast<const short8*>(vbuf + (16 + r16) * 64 + (kc0 ^ 32));
    short8 v20 = *reinterpret_cast<const short8*>(vbuf + (32 + r16) * 64 + kc0);
    short8 v21 = *reinterpret_cast<const short8*>(vbuf + (32 + r16) * 64 + (kc0 ^ 32));
    short8 v30 = *reinterpret_cast<const short8*>(vbuf + (48 + r16) * 64 + kc0);
    short8 v31 = *reinterpret_cast<const short8*>(vbuf + (48 + r16) * 64 + (kc0 ^ 32));

    oacc[0] = __builtin_amdgcn_mfma_f32_16x16x32_bf16(pa0, v00, oacc[0], 0, 0, 0);
    oacc[0] = __builtin_amdgcn_mfma_f32_16x16x32_bf16(pa1, v01, oacc[0], 0, 0, 0);
    oacc[1] = __builtin_amdgcn_mfma_f32_16x16x32_bf16(pa0, v10, oacc[1], 0, 0, 0);
    oacc[1] = __builtin_amdgcn_mfma_f32_16x16x32_bf16(pa1, v11, oacc[1], 0, 0, 0);
    oacc[2] = __builtin_amdgcn_mfma_f32_16x16x32_bf16(pa0, v20, oacc[2], 0, 0, 0);
    oacc[2] = __builtin_amdgcn_mfma_f32_16x16x32_bf16(pa1, v21, oacc[2], 0, 0, 0);
    oacc[3] = __builtin_amdgcn_mfma_f32_16x16x32_bf16(pa0, v30, oacc[3], 0, 0, 0);
    oacc[3] = __builtin_amdgcn_mfma_f32_16x16x32_bf16(pa1, v31, oacc[3], 0, 0, 0);
  }
#undef STAGE

  __syncthreads();  // all waves done with KVl before Olds aliasing

  {
    float rs = l0;
    rs += __shfl_xor(rs, 16);
    rs += __shfl_xor(rs, 32);
    if (g4 == 0) sca_lds[w][r16] = rs;
  }
  f32x4 li = *reinterpret_cast<const f32x4*>(&sca_lds[w][g4 * 4]);
  f32x4 iv;
#pragma unroll
  for (int r = 0; r < 4; r++) iv[r] = 1.f / li[r];
  float* Ow = Olds + w * 16 * 68;
#pragma unroll
  for (int dt = 0; dt < 4; dt++)
#pragma unroll
    for (int r = 0; r < 4; r++)
      Ow[(g4 * 4 + r) * 68 + dt * 16 + r16] = oacc[dt][r] * iv[r];
  {
    int orow = lane >> 2, oc = (lane & 3) * 16;
    int bb = bh / NH, h = bh % NH;
    f32x4 a0 = *reinterpret_cast<const f32x4*>(&Ow[orow * 68 + oc]);
    f32x4 a1 = *reinterpret_cast<const f32x4*>(&Ow[orow * 68 + oc + 4]);
    f32x4 a2 = *reinterpret_cast<const f32x4*>(&Ow[orow * 68 + oc + 8]);
    f32x4 a3 = *reinterpret_cast<const f32x4*>(&Ow[orow * 68 + oc + 12]);
    short8 sa, sb;
#pragma unroll
    for (int j = 0; j < 4; j++) {
      sa[j] = f2bf(a0[j]); sa[4 + j] = f2bf(a1[j]);
      sb[j] = f2bf(a2[j]); sb[4 + j] = f2bf(a3[j]);
    }
    short* dst = &mb[((long)(bb * S_LEN + q0 + orow)) * EMB + h * HD + oc];
    *reinterpret_cast<short8*>(dst) = sa;
    *reinterpret_cast<short8*>(dst + 8) = sb;
  }
}

extern "C" void kernel_launch(void* const* d_in, const int* in_sizes, int n_in,
                              void* d_out, int out_size, void* d_ws, size_t ws_size,
                              hipStream_t stream) {
  const float* x  = (const float*)d_in[0];
  const float* Wq = (const float*)d_in[1];
  const float* Wk = (const float*)d_in[2];
  const float* Wv = (const float*)d_in[3];
  const float* Wo = (const float*)d_in[4];
  const float* bo = (const float*)d_in[5];

  float* out  = (float*)d_out;
  float* outk = out + 3145728;
  float* outv = out + 6291456;

  short* ws  = (short*)d_ws;
  short* xb  = ws;                 // [4096][768]
  short* Wb  = xb + 3145728;       // [2304][768]  (Wq;Wk;Wv)
  short* Wob = Wb + 1769472;       // [768][768]
  short* qb  = Wob + 589824;       // [24][2048][64]
  short* kb  = qb + 3145728;       // [24][2048][64]
  short* vtb = kb + 3145728;       // [24][32][64][64]  (V tiled per 64-row KV tile)
  short* mb  = vtb + 3145728;      // [4096][768]    merged attn, bf16

  cvt_all<<<5376, 256, 0, stream>>>(x, Wq, Wk, Wv, Wo, xb, Wb, Wob);

  gemm_nt<0><<<dim3(18, 32), 256, 0, stream>>>(xb, Wb, outk, outv, qb, kb, vtb, nullptr, nullptr);
  flash_attn15<<<768, 256, 0, stream>>>(qb, kb, vtb, mb);
  gemm_nt<1><<<dim3(6, 32), 256, 0, stream>>>(mb, Wob, nullptr, nullptr, nullptr, nullptr, nullptr, out, bo);
}